// Round 2
// baseline (614.592 us; speedup 1.0000x reference)
//
#include <hip/hip_runtime.h>
#include <hip/hip_bf16.h>

#define B_   32
#define D_   512
#define L_   49
#define E_   4
#define KD_  4
#define NS_  16
#define RK_  32
#define JOBS_ 64

// ---------- helpers ----------
__device__ __forceinline__ float bf2f(unsigned short u){
  union{unsigned int i; float f;} v; v.i = ((unsigned int)u)<<16; return v.f;
}
__device__ __forceinline__ float2 bfp(unsigned int u){
  union{unsigned int i; float f;} a, b; a.i = u<<16; b.i = u & 0xffff0000u;
  return make_float2(a.f, b.f);
}
__device__ __forceinline__ unsigned short f2bfu(float f){
  union{float f; unsigned int i;} u; u.f = f;
  unsigned int r = u.i + 0x7fffu + ((u.i >> 16) & 1u);
  return (unsigned short)(r >> 16);
}
__device__ __forceinline__ float silu_f(float x){ return x / (1.f + expf(-x)); }

// dtype-agnostic loads: bf=1 -> bf16 (ushort), bf=0 -> float32
__device__ __forceinline__ float ldf(const void* p, size_t i, int bf){
  return bf ? bf2f(((const unsigned short*)p)[i]) : ((const float*)p)[i];
}
struct f4s{ float a,b,c,d; };
__device__ __forceinline__ f4s ldf4(const void* p, size_t i, int bf){
  f4s r;
  if (bf){
    uint2 u = *(const uint2*)((const unsigned short*)p + i);
    float2 x = bfp(u.x), y = bfp(u.y);
    r.a=x.x; r.b=x.y; r.c=y.x; r.d=y.y;
  } else {
    float4 v = *(const float4*)((const float*)p + i);
    r.a=v.x; r.b=v.y; r.c=v.z; r.d=v.w;
  }
  return r;
}
struct f8s{ float v[8]; };
__device__ __forceinline__ f8s ldf8(const void* p, size_t i, int bf){
  f8s r;
  if (bf){
    uint4 u = *(const uint4*)((const unsigned short*)p + i);
    float2 x = bfp(u.x), y = bfp(u.y), z = bfp(u.z), w = bfp(u.w);
    r.v[0]=x.x; r.v[1]=x.y; r.v[2]=y.x; r.v[3]=y.y;
    r.v[4]=z.x; r.v[5]=z.y; r.v[6]=w.x; r.v[7]=w.y;
  } else {
    const float4* q = (const float4*)((const float*)p + i);
    float4 a = q[0], b = q[1];
    r.v[0]=a.x; r.v[1]=a.y; r.v[2]=a.z; r.v[3]=a.w;
    r.v[4]=b.x; r.v[5]=b.y; r.v[6]=b.z; r.v[7]=b.w;
  }
  return r;
}

// direction index map: xs[k,d,l] = xc[d, dirmap(k,l)]; output position is the same map.
__device__ __forceinline__ int dirmap(int k, int l){
  if (k == 0) return l;
  if (k == 1) return 48 - l;
  if (k == 2) return (l % 7) * 7 + l / 7;
  int l2 = 48 - l; return (l2 % 7) * 7 + l2 / 7;
}

// ---------- 0. dtype detection ----------
// bf16 N(0,1) data: exponent field of each ushort (viewed as bf16) is in [96,160) ~always.
// fp32 data reinterpreted as ushorts: only ~62% land in that window.
__global__ __launch_bounds__(256) void k_detect(const unsigned short* __restrict__ xr,
                                                int* __restrict__ flag){
  __shared__ int cnt[256];
  int t = threadIdx.x;
  int c = 0;
  #pragma unroll
  for (int i = 0; i < 4; i++){
    unsigned short u = xr[t*4 + i];
    int e = (u >> 7) & 0xff;
    if (e >= 96 && e < 160) c++;
  }
  cnt[t] = c;
  __syncthreads();
  for (int o = 128; o > 0; o >>= 1){
    if (t < o) cnt[t] += cnt[t+o];
    __syncthreads();
  }
  if (t == 0) flag[0] = (cnt[0] >= 900) ? 1 : 0;
}

// ---------- 1. x_flat = mean over 49 positions ----------
__global__ __launch_bounds__(256) void k_xflat(const void* __restrict__ x,
                                               const int* __restrict__ flag,
                                               float* __restrict__ xflat){
  int bf = flag[0];
  int i = blockIdx.x*256 + threadIdx.x;       // 0..16383
  int b = i >> 9, dch = i & 511;
  float s = 0.f;
  for (int l = 0; l < L_; l++) s += ldf(x, ((size_t)(b*L_ + l))*D_ + dch, bf);
  xflat[i] = s * (1.f/49.f);
}

// ---------- 2. gating (single block) ----------
__global__ __launch_bounds__(128) void k_gate(const void* __restrict__ wg,
                                              const void* __restrict__ bg,
                                              const int* __restrict__ flag,
                                              const float* __restrict__ xflat,
                                              int* __restrict__ topi, float* __restrict__ topv,
                                              void* __restrict__ out){
  __shared__ float logits[B_*E_];
  __shared__ float raw[B_*E_];
  __shared__ int   sel[B_];
  __shared__ float den[E_], auxp[E_];
  int bf = flag[0];
  int t = threadIdx.x;
  {
    int b = t >> 2, e = t & 3;
    float acc = ldf(bg, e, bf);
    const float* xr = xflat + b*D_;
    for (int d = 0; d < D_; d++) acc = fmaf(xr[d], ldf(wg, d*E_ + e, bf), acc);
    logits[t] = acc;
  }
  __syncthreads();
  if (t < B_){
    float l0=logits[t*4+0], l1=logits[t*4+1], l2=logits[t*4+2], l3=logits[t*4+3];
    float m = fmaxf(fmaxf(l0,l1), fmaxf(l2,l3));
    float e0=expf(l0-m), e1=expf(l1-m), e2=expf(l2-m), e3=expf(l3-m);
    float s = e0+e1+e2+e3;
    float r[4] = {e0/s, e1/s, e2/s, e3/s};
    int i1 = 0; float v1 = r[0];
    for (int e = 1; e < 4; e++) if (r[e] > v1){ v1 = r[e]; i1 = e; }
    int i2 = -1; float v2 = -1.f;
    for (int e = 0; e < 4; e++){ if (e == i1) continue; if (r[e] > v2){ v2 = r[e]; i2 = e; } }
    if (i1 < 0 || i1 > 3) i1 = 0;
    if (i2 < 0 || i2 > 3) i2 = (i1 + 1) & 3;
    sel[t] = (1<<i1) | (1<<i2);
    for (int e = 0; e < 4; e++) raw[t*4+e] = r[e];
  }
  __syncthreads();
  if (t < E_){
    float dn = 0.f, imp = 0.f, ld = 0.f;
    for (int b = 0; b < B_; b++){
      float r = raw[b*4+t];
      int bit = (sel[b] >> t) & 1;
      if (bit) dn += r;
      imp += r; ld += (float)bit;
    }
    den[t] = dn + 1e-6f;
    imp *= (1.f/B_); ld *= (1.f/B_);
    float df = ld - imp; auxp[t] = df*df;
  }
  __syncthreads();
  if (t == 0){
    float a = 0.01f * 0.25f * (auxp[0]+auxp[1]+auxp[2]+auxp[3]);
    if (bf) ((unsigned short*)out)[16384] = f2bfu(a);
    else    ((float*)out)[16384] = a;
  }
  if (t < B_){
    float gs[4];
    for (int e = 0; e < 4; e++){
      int bit = (sel[t] >> e) & 1;
      gs[e] = bit ? raw[t*4+e] * 40.f / den[e] : 0.f;   // capacity = int(1.25*32) = 40
    }
    int i1 = 0; float v1 = gs[0];
    for (int e = 1; e < 4; e++) if (gs[e] > v1){ v1 = gs[e]; i1 = e; }
    int i2 = -1; float v2 = -1e30f;
    for (int e = 0; e < 4; e++){ if (e == i1) continue; if (gs[e] > v2){ v2 = gs[e]; i2 = e; } }
    if (i1 < 0 || i1 > 3) i1 = 0;
    if (i2 < 0 || i2 > 3) i2 = (i1 + 1) & 3;
    topi[t*2+0] = i1; topv[t*2+0] = v1;
    topi[t*2+1] = i2; topv[t*2+1] = v2;
  }
}

// ---------- 3. in_proj -> xin (fp32) + z (bf16) ----------
__global__ __launch_bounds__(256) void k_inproj(const void* __restrict__ x,
                                                const void* __restrict__ w,
                                                const void* __restrict__ bias,
                                                const int* __restrict__ flag,
                                                const int* __restrict__ topi,
                                                float* __restrict__ xin,
                                                unsigned short* __restrict__ zbuf){
  int bf = flag[0];
  int job = blockIdx.x, lg = blockIdx.y;      // lg < 7, covers l = lg*7 .. lg*7+6
  int t = threadIdx.x;
  int b = job >> 1;
  int e = topi[job];
  __shared__ float xl[D_*8];                   // d-major, 7 l's + 1 pad
  for (int idx = t; idx < D_*7; idx += 256){
    int i = idx >> 9, dd = idx & 511;
    xl[dd*8+i] = ldf(x, ((size_t)(b*L_ + lg*7 + i))*D_ + dd, bf);
  }
  for (int dd = t; dd < D_; dd += 256) xl[dd*8+7] = 0.f;
  __syncthreads();
  float acc[7][4];
  #pragma unroll
  for (int i = 0; i < 7; i++)
    #pragma unroll
    for (int c = 0; c < 4; c++) acc[i][c] = 0.f;
  size_t wbase = (size_t)e*D_*1024 + 4*t;
  for (int d = 0; d < D_; d++){
    f4s wr = ldf4(w, wbase + (size_t)d*1024, bf);
    const float4* xr = (const float4*)&xl[d*8];
    float4 a = xr[0], bb = xr[1];
    float xv[7] = {a.x, a.y, a.z, a.w, bb.x, bb.y, bb.z};
    #pragma unroll
    for (int i = 0; i < 7; i++){
      acc[i][0] = fmaf(xv[i], wr.a, acc[i][0]);
      acc[i][1] = fmaf(xv[i], wr.b, acc[i][1]);
      acc[i][2] = fmaf(xv[i], wr.c, acc[i][2]);
      acc[i][3] = fmaf(xv[i], wr.d, acc[i][3]);
    }
  }
  f4s br = ldf4(bias, (size_t)e*1024 + 4*t, bf);
  #pragma unroll
  for (int i = 0; i < 7; i++){
    float o0 = acc[i][0] + br.a, o1 = acc[i][1] + br.b;
    float o2 = acc[i][2] + br.c, o3 = acc[i][3] + br.d;
    int l = lg*7 + i;
    if (t < 128){
      *(float4*)&xin[((size_t)(job*L_ + l))*D_ + 4*t] = make_float4(o0,o1,o2,o3);
    } else {
      unsigned short* zp = &zbuf[((size_t)(job*L_ + l))*D_ + (4*t - 512)];
      zp[0]=f2bfu(o0); zp[1]=f2bfu(o1); zp[2]=f2bfu(o2); zp[3]=f2bfu(o3);
    }
  }
}

// ---------- 4. depthwise conv 3x3 + bias + silu -> xc[job][p][d] (fp32) ----------
__global__ __launch_bounds__(256) void k_conv(const void* __restrict__ cw,
                                              const void* __restrict__ cb,
                                              const int* __restrict__ flag,
                                              const int* __restrict__ topi,
                                              const float* __restrict__ xin,
                                              float* __restrict__ xc){
  int bf = flag[0];
  int job = blockIdx.x, p = blockIdx.y, t = threadIdx.x;
  int e = topi[job];
  int h = p / 7, w = p % 7;
  const float* xb = xin + (size_t)job*25088;
  #pragma unroll
  for (int rep = 0; rep < 2; rep++){
    int dch = t + rep*256;
    float acc = ldf(cb, e*D_ + dch, bf);
    size_t wp = ((size_t)(e*D_ + dch))*9;
    #pragma unroll
    for (int dy = 0; dy < 3; dy++){
      int hh = h + dy - 1; if (hh < 0 || hh >= 7) continue;
      #pragma unroll
      for (int dx = 0; dx < 3; dx++){
        int ww = w + dx - 1; if (ww < 0 || ww >= 7) continue;
        acc = fmaf(xb[(size_t)(hh*7+ww)*D_ + dch], ldf(cw, wp + dy*3+dx, bf), acc);
      }
    }
    xc[(size_t)job*25088 + (size_t)p*D_ + dch] = acc * (1.f/(1.f+expf(-acc)));
  }
}

// ---------- 5. x_proj: xdbl[job][k][l][c] ----------
__global__ __launch_bounds__(256) void k_xproj(const void* __restrict__ xpw,
                                               const int* __restrict__ flag,
                                               const int* __restrict__ topi,
                                               const float* __restrict__ xc,
                                               float* __restrict__ xdbl){
  int bf = flag[0];
  int job = blockIdx.x, k = blockIdx.y;
  int t = threadIdx.x;
  int c = t & 63, lq = t >> 6;
  int e = topi[job];
  const float* xcb = xc + (size_t)job*25088;
  size_t wbase = (((size_t)(e*KD_+k))*64 + c)*D_;
  float* outb = xdbl + ((size_t)(job*KD_+k))*3136;
  for (int ti = 0; ti < 13; ti++){
    int l = ti*4 + lq;
    if (l >= L_) break;
    int m = dirmap(k, l);
    const float4* row4 = (const float4*)(xcb + (size_t)m*D_);
    float acc = 0.f;
    for (int i = 0; i < 64; i++){
      f8s wv = ldf8(xpw, wbase + 8*i, bf);
      float4 r0 = row4[2*i], r1 = row4[2*i+1];
      acc = fmaf(r0.x, wv.v[0], acc); acc = fmaf(r0.y, wv.v[1], acc);
      acc = fmaf(r0.z, wv.v[2], acc); acc = fmaf(r0.w, wv.v[3], acc);
      acc = fmaf(r1.x, wv.v[4], acc); acc = fmaf(r1.y, wv.v[5], acc);
      acc = fmaf(r1.z, wv.v[6], acc); acc = fmaf(r1.w, wv.v[7], acc);
    }
    outb[l*64 + c] = acc;
  }
}

// ---------- 6. fused dt_proj + softplus + selective scan + combine ----------
__global__ __launch_bounds__(256) void k_scan(const void* __restrict__ dtw,
                                              const void* __restrict__ dtb_,
                                              const void* __restrict__ alog,
                                              const void* __restrict__ ds_,
                                              const int* __restrict__ flag,
                                              const int* __restrict__ topi,
                                              const float* __restrict__ xc,
                                              const float* __restrict__ xdbl,
                                              float* __restrict__ ycomb){
  int bf = flag[0];
  int job = blockIdx.x, k = blockIdx.y, half = blockIdx.z;
  int t = threadIdx.x;
  int d = half*256 + t;
  int e = topi[job];
  __shared__ float xdl[3136];                 // [l][64] : dt(32) | B(16) | C(16)
  const float* src = xdbl + ((size_t)(job*KD_+k))*3136;
  for (int i = t; i < 3136; i += 256) xdl[i] = src[i];
  int ek = e*KD_ + k;
  float w32[RK_];
  #pragma unroll
  for (int q = 0; q < 4; q++){
    f8s wr = ldf8(dtw, ((size_t)ek*D_ + d)*RK_ + q*8, bf);
    #pragma unroll
    for (int j = 0; j < 8; j++) w32[q*8+j] = wr.v[j];
  }
  float A[NS_];
  #pragma unroll
  for (int q = 0; q < 2; q++){
    f8s ar = ldf8(alog, ((size_t)ek*D_ + d)*NS_ + q*8, bf);
    #pragma unroll
    for (int j = 0; j < 8; j++) A[q*8+j] = -expf(ar.v[j]);
  }
  float dtb = ldf(dtb_, (size_t)ek*D_ + d, bf);
  float Dsv = ldf(ds_, (size_t)ek*D_ + d, bf);
  __syncthreads();
  float h[NS_];
  #pragma unroll
  for (int n = 0; n < NS_; n++) h[n] = 0.f;
  const float* xcb = xc + (size_t)job*25088;
  float* ycb = ycomb + (size_t)job*25088;
  for (int l = 0; l < L_; l++){
    const float* xr = &xdl[l*64];
    float dtr = dtb;
    #pragma unroll
    for (int r = 0; r < RK_; r++) dtr = fmaf(xr[r], w32[r], dtr);
    float dt = dtr > 20.f ? dtr : log1pf(expf(dtr));   // softplus
    int m = dirmap(k, l);
    float x_t = xcb[(size_t)m*D_ + d];
    float dtx = dt * x_t;
    float y = 0.f;
    #pragma unroll
    for (int n = 0; n < NS_; n++){
      h[n] = fmaf(h[n], expf(dt*A[n]), dtx * xr[32+n]);
      y = fmaf(h[n], xr[48+n], y);
    }
    atomicAdd(&ycb[(size_t)m*D_ + d], fmaf(Dsv, x_t, y));
  }
}

// ---------- 7. per-job: LN over d at each p, *silu(z), pool, LN, *topv ----------
__device__ __forceinline__ void bred(float& s, float& ss, float* red){
  __syncthreads();
  #pragma unroll
  for (int o = 32; o > 0; o >>= 1){
    s  += __shfl_down(s,  o, 64);
    ss += __shfl_down(ss, o, 64);
  }
  int wid = threadIdx.x >> 6, lane = threadIdx.x & 63;
  if (lane == 0){ red[wid] = s; red[4+wid] = ss; }
  __syncthreads();
  s  = red[0]+red[1]+red[2]+red[3];
  ss = red[4]+red[5]+red[6]+red[7];
}

__global__ __launch_bounds__(256) void k_final(const void* __restrict__ og,
                                               const void* __restrict__ ob,
                                               const void* __restrict__ ng,
                                               const void* __restrict__ nb,
                                               const int* __restrict__ flag,
                                               const int* __restrict__ topi,
                                               const float* __restrict__ topv,
                                               const float* __restrict__ ycomb,
                                               const unsigned short* __restrict__ zbuf,
                                               float* __restrict__ slot){
  __shared__ float red[8];
  int bf = flag[0];
  int job = blockIdx.x, t = threadIdx.x;
  int e = topi[job]; float gv = topv[job];
  int d0 = t, d1 = t + 256;
  const float* yc = ycomb + (size_t)job*25088;
  const unsigned short* zb = zbuf + (size_t)job*25088;
  float g0 = ldf(og, e*D_+d0, bf), g1 = ldf(og, e*D_+d1, bf);
  float o0 = ldf(ob, e*D_+d0, bf), o1 = ldf(ob, e*D_+d1, bf);
  float p0 = 0.f, p1 = 0.f;
  for (int p = 0; p < L_; p++){
    float v0 = yc[p*D_+d0], v1 = yc[p*D_+d1];
    float s = v0+v1, ss = v0*v0 + v1*v1;
    bred(s, ss, red);
    float mu = s*(1.f/512.f);
    float var = ss*(1.f/512.f) - mu*mu;
    float rs = rsqrtf(var + 1e-5f);
    float z0 = bf2f(zb[p*D_ + d0]), z1 = bf2f(zb[p*D_ + d1]);
    p0 += ((v0-mu)*rs*g0 + o0) * silu_f(z0);
    p1 += ((v1-mu)*rs*g1 + o1) * silu_f(z1);
  }
  p0 *= (1.f/49.f); p1 *= (1.f/49.f);
  float s = p0+p1, ss = p0*p0 + p1*p1;
  bred(s, ss, red);
  float mu = s*(1.f/512.f);
  float var = ss*(1.f/512.f) - mu*mu;
  float rs = rsqrtf(var + 1e-5f);
  slot[(size_t)job*D_ + d0] = ((p0-mu)*rs*ldf(ng, e*D_+d0, bf) + ldf(nb, e*D_+d0, bf)) * gv;
  slot[(size_t)job*D_ + d1] = ((p1-mu)*rs*ldf(ng, e*D_+d1, bf) + ldf(nb, e*D_+d1, bf)) * gv;
}

// ---------- 8. mix the two slots per batch -> out ----------
__global__ __launch_bounds__(256) void k_mix(const float* __restrict__ slot,
                                             const int* __restrict__ flag,
                                             void* __restrict__ out){
  int bf = flag[0];
  int i = blockIdx.x*256 + threadIdx.x;       // 0..16383
  int b = i >> 9, d = i & 511;
  float v = slot[(size_t)(2*b)*D_ + d] + slot[(size_t)(2*b+1)*D_ + d];
  if (bf) ((unsigned short*)out)[i] = f2bfu(v);
  else    ((float*)out)[i] = v;
}

extern "C" void kernel_launch(void* const* d_in, const int* in_sizes, int n_in,
                              void* d_out, int out_size, void* d_ws, size_t ws_size,
                              hipStream_t stream){
  const void* x    = d_in[0];
  const void* wg   = d_in[1];
  const void* bg   = d_in[2];
  const void* ipw  = d_in[3];
  const void* ipb  = d_in[4];
  const void* cw   = d_in[5];
  const void* cb   = d_in[6];
  const void* xpw  = d_in[7];
  const void* dtw  = d_in[8];
  const void* dtb  = d_in[9];
  const void* alog = d_in[10];
  const void* dss  = d_in[11];
  const void* ogg  = d_in[12];
  const void* obb  = d_in[13];
  const void* ngg  = d_in[14];
  const void* nbb  = d_in[15];
  float* wsf = (float*)d_ws;
  int*   flag  = (int*)d_ws;                         // [0]
  int*   topi  = (int*)d_ws + 16;                    // 16..80
  float* topv  = wsf + 96;                           // 96..160
  float* xflat = wsf + 256;                          // 16384
  float* xc    = wsf + 16640;                        // 64*49*512 = 1605632
  float* xdbl  = wsf + 1622272;                      // 64*4*49*64 = 802816
  float* r1    = wsf + 2425088;                      // xin, later ycomb: 1605632
  unsigned short* zbuf = (unsigned short*)(wsf + 4030720); // 1605632 bf16
  float* slot  = wsf + 4833536;                      // 64*512 = 32768 (end 4866304 fl ~ 18.6MB)

  k_detect<<<1, 256, 0, stream>>>((const unsigned short*)x, flag);
  k_xflat <<<64, 256, 0, stream>>>(x, flag, xflat);
  k_gate  <<<1, 128, 0, stream>>>(wg, bg, flag, xflat, topi, topv, d_out);
  k_inproj<<<dim3(64,7),  256, 0, stream>>>(x, ipw, ipb, flag, topi, r1, zbuf);
  k_conv  <<<dim3(64,49), 256, 0, stream>>>(cw, cb, flag, topi, r1, xc);
  hipMemsetAsync(r1, 0, (size_t)1605632*4, stream);  // r1 becomes ycomb
  k_xproj <<<dim3(64,4),  256, 0, stream>>>(xpw, flag, topi, xc, xdbl);
  k_scan  <<<dim3(64,4,2),256, 0, stream>>>(dtw, dtb, alog, dss, flag, topi, xc, xdbl, r1);
  k_final <<<64, 256, 0, stream>>>(ogg, obb, ngg, nbb, flag, topi, topv, r1, zbuf, slot);
  k_mix   <<<64, 256, 0, stream>>>(slot, flag, d_out);
}

// Round 3
// 450.865 us; speedup vs baseline: 1.3631x; 1.3631x over previous
//
#include <hip/hip_runtime.h>
#include <hip/hip_bf16.h>

#define B_   32
#define D_   512
#define L_   49
#define E_   4
#define KD_  4
#define NS_  16
#define RK_  32
#define JOBS_ 64

// ---------- helpers ----------
__device__ __forceinline__ float bf2f(unsigned short u){
  union{unsigned int i; float f;} v; v.i = ((unsigned int)u)<<16; return v.f;
}
__device__ __forceinline__ float2 bfp(unsigned int u){
  union{unsigned int i; float f;} a, b; a.i = u<<16; b.i = u & 0xffff0000u;
  return make_float2(a.f, b.f);
}
__device__ __forceinline__ unsigned short f2bfu(float f){
  union{float f; unsigned int i;} u; u.f = f;
  unsigned int r = u.i + 0x7fffu + ((u.i >> 16) & 1u);
  return (unsigned short)(r >> 16);
}
__device__ __forceinline__ float silu_f(float x){ return x / (1.f + expf(-x)); }

// dtype-agnostic loads: bf=1 -> bf16 (ushort), bf=0 -> float32
__device__ __forceinline__ float ldf(const void* p, size_t i, int bf){
  return bf ? bf2f(((const unsigned short*)p)[i]) : ((const float*)p)[i];
}
struct f4s{ float a,b,c,d; };
__device__ __forceinline__ f4s ldf4(const void* p, size_t i, int bf){
  f4s r;
  if (bf){
    uint2 u = *(const uint2*)((const unsigned short*)p + i);
    float2 x = bfp(u.x), y = bfp(u.y);
    r.a=x.x; r.b=x.y; r.c=y.x; r.d=y.y;
  } else {
    float4 v = *(const float4*)((const float*)p + i);
    r.a=v.x; r.b=v.y; r.c=v.z; r.d=v.w;
  }
  return r;
}
struct f8s{ float v[8]; };
__device__ __forceinline__ f8s ldf8(const void* p, size_t i, int bf){
  f8s r;
  if (bf){
    uint4 u = *(const uint4*)((const unsigned short*)p + i);
    float2 x = bfp(u.x), y = bfp(u.y), z = bfp(u.z), w = bfp(u.w);
    r.v[0]=x.x; r.v[1]=x.y; r.v[2]=y.x; r.v[3]=y.y;
    r.v[4]=z.x; r.v[5]=z.y; r.v[6]=w.x; r.v[7]=w.y;
  } else {
    const float4* q = (const float4*)((const float*)p + i);
    float4 a = q[0], b = q[1];
    r.v[0]=a.x; r.v[1]=a.y; r.v[2]=a.z; r.v[3]=a.w;
    r.v[4]=b.x; r.v[5]=b.y; r.v[6]=b.z; r.v[7]=b.w;
  }
  return r;
}

// direction index map: xs[k,d,l] = xc[d, dirmap(k,l)]; output position is the same map.
__device__ __forceinline__ int dirmap(int k, int l){
  if (k == 0) return l;
  if (k == 1) return 48 - l;
  if (k == 2) return (l % 7) * 7 + l / 7;
  int l2 = 48 - l; return (l2 % 7) * 7 + l2 / 7;
}

// ---------- 0. dtype detection ----------
__global__ __launch_bounds__(256) void k_detect(const unsigned short* __restrict__ xr,
                                                int* __restrict__ flag){
  __shared__ int cnt[256];
  int t = threadIdx.x;
  int c = 0;
  #pragma unroll
  for (int i = 0; i < 4; i++){
    unsigned short u = xr[t*4 + i];
    int e = (u >> 7) & 0xff;
    if (e >= 96 && e < 160) c++;
  }
  cnt[t] = c;
  __syncthreads();
  for (int o = 128; o > 0; o >>= 1){
    if (t < o) cnt[t] += cnt[t+o];
    __syncthreads();
  }
  if (t == 0) flag[0] = (cnt[0] >= 900) ? 1 : 0;
}

// ---------- 1. x_flat = mean over 49 positions ----------
__global__ __launch_bounds__(256) void k_xflat(const void* __restrict__ x,
                                               const int* __restrict__ flag,
                                               float* __restrict__ xflat){
  int bf = flag[0];
  int i = blockIdx.x*256 + threadIdx.x;       // 0..16383
  int b = i >> 9, dch = i & 511;
  float s = 0.f;
  for (int l = 0; l < L_; l++) s += ldf(x, ((size_t)(b*L_ + l))*D_ + dch, bf);
  xflat[i] = s * (1.f/49.f);
}

// ---------- 2. gating (single block) ----------
__global__ __launch_bounds__(128) void k_gate(const void* __restrict__ wg,
                                              const void* __restrict__ bg,
                                              const int* __restrict__ flag,
                                              const float* __restrict__ xflat,
                                              int* __restrict__ topi, float* __restrict__ topv,
                                              void* __restrict__ out){
  __shared__ float logits[B_*E_];
  __shared__ float raw[B_*E_];
  __shared__ int   sel[B_];
  __shared__ float den[E_], auxp[E_];
  int bf = flag[0];
  int t = threadIdx.x;
  {
    int b = t >> 2, e = t & 3;
    float acc = ldf(bg, e, bf);
    const float* xr = xflat + b*D_;
    for (int d = 0; d < D_; d++) acc = fmaf(xr[d], ldf(wg, d*E_ + e, bf), acc);
    logits[t] = acc;
  }
  __syncthreads();
  if (t < B_){
    float l0=logits[t*4+0], l1=logits[t*4+1], l2=logits[t*4+2], l3=logits[t*4+3];
    float m = fmaxf(fmaxf(l0,l1), fmaxf(l2,l3));
    float e0=expf(l0-m), e1=expf(l1-m), e2=expf(l2-m), e3=expf(l3-m);
    float s = e0+e1+e2+e3;
    float r[4] = {e0/s, e1/s, e2/s, e3/s};
    int i1 = 0; float v1 = r[0];
    for (int e = 1; e < 4; e++) if (r[e] > v1){ v1 = r[e]; i1 = e; }
    int i2 = -1; float v2 = -1.f;
    for (int e = 0; e < 4; e++){ if (e == i1) continue; if (r[e] > v2){ v2 = r[e]; i2 = e; } }
    if (i1 < 0 || i1 > 3) i1 = 0;
    if (i2 < 0 || i2 > 3) i2 = (i1 + 1) & 3;
    sel[t] = (1<<i1) | (1<<i2);
    for (int e = 0; e < 4; e++) raw[t*4+e] = r[e];
  }
  __syncthreads();
  if (t < E_){
    float dn = 0.f, imp = 0.f, ld = 0.f;
    for (int b = 0; b < B_; b++){
      float r = raw[b*4+t];
      int bit = (sel[b] >> t) & 1;
      if (bit) dn += r;
      imp += r; ld += (float)bit;
    }
    den[t] = dn + 1e-6f;
    imp *= (1.f/B_); ld *= (1.f/B_);
    float df = ld - imp; auxp[t] = df*df;
  }
  __syncthreads();
  if (t == 0){
    float a = 0.01f * 0.25f * (auxp[0]+auxp[1]+auxp[2]+auxp[3]);
    if (bf) ((unsigned short*)out)[16384] = f2bfu(a);
    else    ((float*)out)[16384] = a;
  }
  if (t < B_){
    float gs[4];
    for (int e = 0; e < 4; e++){
      int bit = (sel[t] >> e) & 1;
      gs[e] = bit ? raw[t*4+e] * 40.f / den[e] : 0.f;   // capacity = int(1.25*32) = 40
    }
    int i1 = 0; float v1 = gs[0];
    for (int e = 1; e < 4; e++) if (gs[e] > v1){ v1 = gs[e]; i1 = e; }
    int i2 = -1; float v2 = -1e30f;
    for (int e = 0; e < 4; e++){ if (e == i1) continue; if (gs[e] > v2){ v2 = gs[e]; i2 = e; } }
    if (i1 < 0 || i1 > 3) i1 = 0;
    if (i2 < 0 || i2 > 3) i2 = (i1 + 1) & 3;
    topi[t*2+0] = i1; topv[t*2+0] = v1;
    topi[t*2+1] = i2; topv[t*2+1] = v2;
  }
}

// ---------- 3. in_proj -> xin (fp32) + z (bf16) ----------
__global__ __launch_bounds__(256) void k_inproj(const void* __restrict__ x,
                                                const void* __restrict__ w,
                                                const void* __restrict__ bias,
                                                const int* __restrict__ flag,
                                                const int* __restrict__ topi,
                                                float* __restrict__ xin,
                                                unsigned short* __restrict__ zbuf){
  int bf = flag[0];
  int job = blockIdx.x, lg = blockIdx.y;      // lg < 7, covers l = lg*7 .. lg*7+6
  int t = threadIdx.x;
  int b = job >> 1;
  int e = topi[job];
  __shared__ float xl[D_*8];                   // d-major, 7 l's + 1 pad
  for (int idx = t; idx < D_*7; idx += 256){
    int i = idx >> 9, dd = idx & 511;
    xl[dd*8+i] = ldf(x, ((size_t)(b*L_ + lg*7 + i))*D_ + dd, bf);
  }
  for (int dd = t; dd < D_; dd += 256) xl[dd*8+7] = 0.f;
  __syncthreads();
  float acc[7][4];
  #pragma unroll
  for (int i = 0; i < 7; i++)
    #pragma unroll
    for (int c = 0; c < 4; c++) acc[i][c] = 0.f;
  size_t wbase = (size_t)e*D_*1024 + 4*t;
  for (int d = 0; d < D_; d++){
    f4s wr = ldf4(w, wbase + (size_t)d*1024, bf);
    const float4* xr = (const float4*)&xl[d*8];
    float4 a = xr[0], bb = xr[1];
    float xv[7] = {a.x, a.y, a.z, a.w, bb.x, bb.y, bb.z};
    #pragma unroll
    for (int i = 0; i < 7; i++){
      acc[i][0] = fmaf(xv[i], wr.a, acc[i][0]);
      acc[i][1] = fmaf(xv[i], wr.b, acc[i][1]);
      acc[i][2] = fmaf(xv[i], wr.c, acc[i][2]);
      acc[i][3] = fmaf(xv[i], wr.d, acc[i][3]);
    }
  }
  f4s br = ldf4(bias, (size_t)e*1024 + 4*t, bf);
  #pragma unroll
  for (int i = 0; i < 7; i++){
    float o0 = acc[i][0] + br.a, o1 = acc[i][1] + br.b;
    float o2 = acc[i][2] + br.c, o3 = acc[i][3] + br.d;
    int l = lg*7 + i;
    if (t < 128){
      *(float4*)&xin[((size_t)(job*L_ + l))*D_ + 4*t] = make_float4(o0,o1,o2,o3);
    } else {
      unsigned short* zp = &zbuf[((size_t)(job*L_ + l))*D_ + (4*t - 512)];
      zp[0]=f2bfu(o0); zp[1]=f2bfu(o1); zp[2]=f2bfu(o2); zp[3]=f2bfu(o3);
    }
  }
}

// ---------- 4. depthwise conv 3x3 + bias + silu -> xc[job][p][d] (fp32) ----------
__global__ __launch_bounds__(256) void k_conv(const void* __restrict__ cw,
                                              const void* __restrict__ cb,
                                              const int* __restrict__ flag,
                                              const int* __restrict__ topi,
                                              const float* __restrict__ xin,
                                              float* __restrict__ xc){
  int bf = flag[0];
  int job = blockIdx.x, p = blockIdx.y, t = threadIdx.x;
  int e = topi[job];
  int h = p / 7, w = p % 7;
  const float* xb = xin + (size_t)job*25088;
  #pragma unroll
  for (int rep = 0; rep < 2; rep++){
    int dch = t + rep*256;
    float acc = ldf(cb, e*D_ + dch, bf);
    size_t wp = ((size_t)(e*D_ + dch))*9;
    #pragma unroll
    for (int dy = 0; dy < 3; dy++){
      int hh = h + dy - 1; if (hh < 0 || hh >= 7) continue;
      #pragma unroll
      for (int dx = 0; dx < 3; dx++){
        int ww = w + dx - 1; if (ww < 0 || ww >= 7) continue;
        acc = fmaf(xb[(size_t)(hh*7+ww)*D_ + dch], ldf(cw, wp + dy*3+dx, bf), acc);
      }
    }
    xc[(size_t)job*25088 + (size_t)p*D_ + dch] = acc * (1.f/(1.f+expf(-acc)));
  }
}

// ---------- 5. x_proj (REWRITTEN): LDS-staged weights, coalesced ----------
__global__ __launch_bounds__(256) void k_xproj(const void* __restrict__ xpw,
                                               const int* __restrict__ flag,
                                               const int* __restrict__ topi,
                                               const float* __restrict__ xc,
                                               float* __restrict__ xdbl){
  int bf = flag[0];
  int job = blockIdx.x, k = blockIdx.y, z = blockIdx.z;
  int t = threadIdx.x;
  int c = t & 63, lq = t >> 6;                 // lq = wave id (l is wave-uniform)
  int e = topi[job];
  __shared__ unsigned short wl[64*512];        // 64 KB, packed [s][c][8], s = d/8
  size_t wgbase = ((size_t)(e*KD_+k))*64*512;
  #pragma unroll
  for (int it = 0; it < 16; it++){
    int idx = it*256 + t;                      // ushort8-chunk id, 4096 total
    int cc = idx >> 6, s = idx & 63;
    unsigned short* dst = &wl[s*512 + cc*8];
    if (bf){
      *(uint4*)dst = *(const uint4*)((const unsigned short*)xpw + wgbase + (size_t)cc*512 + s*8);
    } else {
      const float4* g = (const float4*)((const float*)xpw + wgbase + (size_t)cc*512 + s*8);
      float4 a = g[0], b = g[1];
      dst[0]=f2bfu(a.x); dst[1]=f2bfu(a.y); dst[2]=f2bfu(a.z); dst[3]=f2bfu(a.w);
      dst[4]=f2bfu(b.x); dst[5]=f2bfu(b.y); dst[6]=f2bfu(b.z); dst[7]=f2bfu(b.w);
    }
  }
  __syncthreads();
  const float* xcb = xc + (size_t)job*25088;
  float* outb = xdbl + ((size_t)(job*KD_+k))*3136;
  #pragma unroll
  for (int ti = 0; ti < 7; ti++){
    int l2 = ti*4 + lq;                        // 0..27
    int l = 2*l2 + z;                          // even/odd split over blockIdx.z
    if (l >= L_) continue;
    int m = dirmap(k, l);
    const float4* xr = (const float4*)(xcb + (size_t)m*D_);
    float a0=0.f, a1=0.f, a2=0.f, a3=0.f;
    for (int s = 0; s < 64; s++){
      uint4 w = *(const uint4*)&wl[s*512 + c*8];
      float4 x0 = xr[2*s], x1 = xr[2*s+1];
      float2 p0 = bfp(w.x), p1 = bfp(w.y), p2 = bfp(w.z), p3 = bfp(w.w);
      a0 = fmaf(x0.x, p0.x, a0); a1 = fmaf(x0.y, p0.y, a1);
      a2 = fmaf(x0.z, p1.x, a2); a3 = fmaf(x0.w, p1.y, a3);
      a0 = fmaf(x1.x, p2.x, a0); a1 = fmaf(x1.y, p2.y, a1);
      a2 = fmaf(x1.z, p3.x, a2); a3 = fmaf(x1.w, p3.y, a3);
    }
    outb[l*64 + c] = (a0+a1)+(a2+a3);
  }
}

// ---------- 6. fused dt_proj + softplus + selective scan + combine ----------
__global__ __launch_bounds__(256) void k_scan(const void* __restrict__ dtw,
                                              const void* __restrict__ dtb_,
                                              const void* __restrict__ alog,
                                              const void* __restrict__ ds_,
                                              const int* __restrict__ flag,
                                              const int* __restrict__ topi,
                                              const float* __restrict__ xc,
                                              const float* __restrict__ xdbl,
                                              float* __restrict__ ycomb){
  int bf = flag[0];
  int job = blockIdx.x, k = blockIdx.y, half = blockIdx.z;
  int t = threadIdx.x;
  int d = half*256 + t;
  int e = topi[job];
  __shared__ float xdl[3136];                 // [l][64] : dt(32) | B(16) | C(16)
  const float* src = xdbl + ((size_t)(job*KD_+k))*3136;
  for (int i = t; i < 3136; i += 256) xdl[i] = src[i];
  int ek = e*KD_ + k;
  float w32[RK_];
  #pragma unroll
  for (int q = 0; q < 4; q++){
    f8s wr = ldf8(dtw, ((size_t)ek*D_ + d)*RK_ + q*8, bf);
    #pragma unroll
    for (int j = 0; j < 8; j++) w32[q*8+j] = wr.v[j];
  }
  float A[NS_];
  #pragma unroll
  for (int q = 0; q < 2; q++){
    f8s ar = ldf8(alog, ((size_t)ek*D_ + d)*NS_ + q*8, bf);
    #pragma unroll
    for (int j = 0; j < 8; j++) A[q*8+j] = -expf(ar.v[j]);
  }
  float dtb = ldf(dtb_, (size_t)ek*D_ + d, bf);
  float Dsv = ldf(ds_, (size_t)ek*D_ + d, bf);
  __syncthreads();
  float h[NS_];
  #pragma unroll
  for (int n = 0; n < NS_; n++) h[n] = 0.f;
  const float* xcb = xc + (size_t)job*25088;
  float* ycb = ycomb + (size_t)job*25088;
  for (int l = 0; l < L_; l++){
    const float* xr = &xdl[l*64];
    float dtr = dtb;
    #pragma unroll
    for (int r = 0; r < RK_; r++) dtr = fmaf(xr[r], w32[r], dtr);
    float dt = dtr > 20.f ? dtr : log1pf(expf(dtr));   // softplus
    int m = dirmap(k, l);
    float x_t = xcb[(size_t)m*D_ + d];
    float dtx = dt * x_t;
    float y = 0.f;
    #pragma unroll
    for (int n = 0; n < NS_; n++){
      h[n] = fmaf(h[n], expf(dt*A[n]), dtx * xr[32+n]);
      y = fmaf(h[n], xr[48+n], y);
    }
    atomicAdd(&ycb[(size_t)m*D_ + d], fmaf(Dsv, x_t, y));
  }
}

// ---------- 7. per-job: LN over d at each p, *silu(z), pool, LN, *topv ----------
__device__ __forceinline__ void bred(float& s, float& ss, float* red){
  __syncthreads();
  #pragma unroll
  for (int o = 32; o > 0; o >>= 1){
    s  += __shfl_down(s,  o, 64);
    ss += __shfl_down(ss, o, 64);
  }
  int wid = threadIdx.x >> 6, lane = threadIdx.x & 63;
  if (lane == 0){ red[wid] = s; red[4+wid] = ss; }
  __syncthreads();
  s  = red[0]+red[1]+red[2]+red[3];
  ss = red[4]+red[5]+red[6]+red[7];
}

__global__ __launch_bounds__(256) void k_final(const void* __restrict__ og,
                                               const void* __restrict__ ob,
                                               const void* __restrict__ ng,
                                               const void* __restrict__ nb,
                                               const int* __restrict__ flag,
                                               const int* __restrict__ topi,
                                               const float* __restrict__ topv,
                                               const float* __restrict__ ycomb,
                                               const unsigned short* __restrict__ zbuf,
                                               float* __restrict__ slot){
  __shared__ float red[8];
  int bf = flag[0];
  int job = blockIdx.x, t = threadIdx.x;
  int e = topi[job]; float gv = topv[job];
  int d0 = t, d1 = t + 256;
  const float* yc = ycomb + (size_t)job*25088;
  const unsigned short* zb = zbuf + (size_t)job*25088;
  float g0 = ldf(og, e*D_+d0, bf), g1 = ldf(og, e*D_+d1, bf);
  float o0 = ldf(ob, e*D_+d0, bf), o1 = ldf(ob, e*D_+d1, bf);
  float p0 = 0.f, p1 = 0.f;
  for (int p = 0; p < L_; p++){
    float v0 = yc[p*D_+d0], v1 = yc[p*D_+d1];
    float s = v0+v1, ss = v0*v0 + v1*v1;
    bred(s, ss, red);
    float mu = s*(1.f/512.f);
    float var = ss*(1.f/512.f) - mu*mu;
    float rs = rsqrtf(var + 1e-5f);
    float z0 = bf2f(zb[p*D_ + d0]), z1 = bf2f(zb[p*D_ + d1]);
    p0 += ((v0-mu)*rs*g0 + o0) * silu_f(z0);
    p1 += ((v1-mu)*rs*g1 + o1) * silu_f(z1);
  }
  p0 *= (1.f/49.f); p1 *= (1.f/49.f);
  float s = p0+p1, ss = p0*p0 + p1*p1;
  bred(s, ss, red);
  float mu = s*(1.f/512.f);
  float var = ss*(1.f/512.f) - mu*mu;
  float rs = rsqrtf(var + 1e-5f);
  slot[(size_t)job*D_ + d0] = ((p0-mu)*rs*ldf(ng, e*D_+d0, bf) + ldf(nb, e*D_+d0, bf)) * gv;
  slot[(size_t)job*D_ + d1] = ((p1-mu)*rs*ldf(ng, e*D_+d1, bf) + ldf(nb, e*D_+d1, bf)) * gv;
}

// ---------- 8. mix the two slots per batch -> out ----------
__global__ __launch_bounds__(256) void k_mix(const float* __restrict__ slot,
                                             const int* __restrict__ flag,
                                             void* __restrict__ out){
  int bf = flag[0];
  int i = blockIdx.x*256 + threadIdx.x;       // 0..16383
  int b = i >> 9, d = i & 511;
  float v = slot[(size_t)(2*b)*D_ + d] + slot[(size_t)(2*b+1)*D_ + d];
  if (bf) ((unsigned short*)out)[i] = f2bfu(v);
  else    ((float*)out)[i] = v;
}

extern "C" void kernel_launch(void* const* d_in, const int* in_sizes, int n_in,
                              void* d_out, int out_size, void* d_ws, size_t ws_size,
                              hipStream_t stream){
  const void* x    = d_in[0];
  const void* wg   = d_in[1];
  const void* bg   = d_in[2];
  const void* ipw  = d_in[3];
  const void* ipb  = d_in[4];
  const void* cw   = d_in[5];
  const void* cb   = d_in[6];
  const void* xpw  = d_in[7];
  const void* dtw  = d_in[8];
  const void* dtb  = d_in[9];
  const void* alog = d_in[10];
  const void* dss  = d_in[11];
  const void* ogg  = d_in[12];
  const void* obb  = d_in[13];
  const void* ngg  = d_in[14];
  const void* nbb  = d_in[15];
  float* wsf = (float*)d_ws;
  int*   flag  = (int*)d_ws;                         // [0]
  int*   topi  = (int*)d_ws + 16;                    // 16..80
  float* topv  = wsf + 96;                           // 96..160
  float* xflat = wsf + 256;                          // 16384
  float* xc    = wsf + 16640;                        // 64*49*512 = 1605632
  float* xdbl  = wsf + 1622272;                      // 64*4*49*64 = 802816
  float* r1    = wsf + 2425088;                      // xin, later ycomb: 1605632
  unsigned short* zbuf = (unsigned short*)(wsf + 4030720); // 1605632 bf16
  float* slot  = wsf + 4833536;                      // 64*512 = 32768 (end ~18.6MB)

  k_detect<<<1, 256, 0, stream>>>((const unsigned short*)x, flag);
  k_xflat <<<64, 256, 0, stream>>>(x, flag, xflat);
  k_gate  <<<1, 128, 0, stream>>>(wg, bg, flag, xflat, topi, topv, d_out);
  k_inproj<<<dim3(64,7),  256, 0, stream>>>(x, ipw, ipb, flag, topi, r1, zbuf);
  k_conv  <<<dim3(64,49), 256, 0, stream>>>(cw, cb, flag, topi, r1, xc);
  hipMemsetAsync(r1, 0, (size_t)1605632*4, stream);  // r1 becomes ycomb
  k_xproj <<<dim3(64,4,2),256, 0, stream>>>(xpw, flag, topi, xc, xdbl);
  k_scan  <<<dim3(64,4,2),256, 0, stream>>>(dtw, dtb, alog, dss, flag, topi, xc, xdbl, r1);
  k_final <<<64, 256, 0, stream>>>(ogg, obb, ngg, nbb, flag, topi, topv, r1, zbuf, slot);
  k_mix   <<<64, 256, 0, stream>>>(slot, flag, d_out);
}

// Round 4
// 388.581 us; speedup vs baseline: 1.5816x; 1.1603x over previous
//
#include <hip/hip_runtime.h>
#include <hip/hip_bf16.h>

#define B_   32
#define D_   512
#define L_   49
#define E_   4
#define KD_  4
#define NS_  16
#define RK_  32
#define JOBS_ 64

typedef short s16x8 __attribute__((ext_vector_type(8)));
typedef float f32x4v __attribute__((ext_vector_type(4)));
union U4 { uint4 u; s16x8 s; };

// ---------- helpers ----------
__device__ __forceinline__ float bf2f(unsigned short u){
  union{unsigned int i; float f;} v; v.i = ((unsigned int)u)<<16; return v.f;
}
__device__ __forceinline__ float2 bfp(unsigned int u){
  union{unsigned int i; float f;} a, b; a.i = u<<16; b.i = u & 0xffff0000u;
  return make_float2(a.f, b.f);
}
__device__ __forceinline__ unsigned short f2bfu(float f){
  union{float f; unsigned int i;} u; u.f = f;
  unsigned int r = u.i + 0x7fffu + ((u.i >> 16) & 1u);
  return (unsigned short)(r >> 16);
}
__device__ __forceinline__ float silu_f(float x){ return x / (1.f + expf(-x)); }

// dtype-agnostic loads: bf=1 -> bf16 (ushort), bf=0 -> float32
__device__ __forceinline__ float ldf(const void* p, size_t i, int bf){
  return bf ? bf2f(((const unsigned short*)p)[i]) : ((const float*)p)[i];
}
struct f4s{ float a,b,c,d; };
__device__ __forceinline__ f4s ldf4(const void* p, size_t i, int bf){
  f4s r;
  if (bf){
    uint2 u = *(const uint2*)((const unsigned short*)p + i);
    float2 x = bfp(u.x), y = bfp(u.y);
    r.a=x.x; r.b=x.y; r.c=y.x; r.d=y.y;
  } else {
    float4 v = *(const float4*)((const float*)p + i);
    r.a=v.x; r.b=v.y; r.c=v.z; r.d=v.w;
  }
  return r;
}
struct f8s{ float v[8]; };
__device__ __forceinline__ f8s ldf8(const void* p, size_t i, int bf){
  f8s r;
  if (bf){
    uint4 u = *(const uint4*)((const unsigned short*)p + i);
    float2 x = bfp(u.x), y = bfp(u.y), z = bfp(u.z), w = bfp(u.w);
    r.v[0]=x.x; r.v[1]=x.y; r.v[2]=y.x; r.v[3]=y.y;
    r.v[4]=z.x; r.v[5]=z.y; r.v[6]=w.x; r.v[7]=w.y;
  } else {
    const float4* q = (const float4*)((const float*)p + i);
    float4 a = q[0], b = q[1];
    r.v[0]=a.x; r.v[1]=a.y; r.v[2]=a.z; r.v[3]=a.w;
    r.v[4]=b.x; r.v[5]=b.y; r.v[6]=b.z; r.v[7]=b.w;
  }
  return r;
}

// direction index map: xs[k,d,l] = xc[d, dirmap(k,l)]; output position is the same map.
__device__ __forceinline__ int dirmap(int k, int l){
  if (k == 0) return l;
  if (k == 1) return 48 - l;
  if (k == 2) return (l % 7) * 7 + l / 7;
  int l2 = 48 - l; return (l2 % 7) * 7 + l2 / 7;
}

// ---------- 0. dtype detection ----------
__global__ __launch_bounds__(256) void k_detect(const unsigned short* __restrict__ xr,
                                                int* __restrict__ flag){
  __shared__ int cnt[256];
  int t = threadIdx.x;
  int c = 0;
  #pragma unroll
  for (int i = 0; i < 4; i++){
    unsigned short u = xr[t*4 + i];
    int e = (u >> 7) & 0xff;
    if (e >= 96 && e < 160) c++;
  }
  cnt[t] = c;
  __syncthreads();
  for (int o = 128; o > 0; o >>= 1){
    if (t < o) cnt[t] += cnt[t+o];
    __syncthreads();
  }
  if (t == 0) flag[0] = (cnt[0] >= 900) ? 1 : 0;
}

// ---------- 0b. transpose in_proj weights: W[e][d][c] -> WT[e][c][d] (bf16) ----------
__global__ __launch_bounds__(256) void k_wtrans(const void* __restrict__ w,
                                                const int* __restrict__ flag,
                                                unsigned short* __restrict__ wt){
  __shared__ unsigned short tile[64][72];     // [c][d], stride 144 B (16-aligned)
  int e = blockIdx.x, cb = blockIdx.y, db = blockIdx.z;
  int bf = flag[0];
  int t = threadIdx.x;
  #pragma unroll
  for (int r = 0; r < 4; r++){
    int d  = r*16 + (t>>4);
    int c0 = (t&15)*4;
    size_t g = ((size_t)e*512 + db*64 + d)*1024 + cb*64 + c0;
    if (bf){
      uint2 u = *(const uint2*)((const unsigned short*)w + g);
      tile[c0+0][d] = (unsigned short)(u.x & 0xffffu);
      tile[c0+1][d] = (unsigned short)(u.x >> 16);
      tile[c0+2][d] = (unsigned short)(u.y & 0xffffu);
      tile[c0+3][d] = (unsigned short)(u.y >> 16);
    } else {
      float4 v = *(const float4*)((const float*)w + g);
      tile[c0+0][d] = f2bfu(v.x);
      tile[c0+1][d] = f2bfu(v.y);
      tile[c0+2][d] = f2bfu(v.z);
      tile[c0+3][d] = f2bfu(v.w);
    }
  }
  __syncthreads();
  #pragma unroll
  for (int r = 0; r < 2; r++){
    int o = r*256 + t;
    int c = o >> 3, d0 = (o & 7)*8;
    uint4 v = *(const uint4*)&tile[c][d0];
    *(uint4*)(wt + ((size_t)e*1024 + cb*64 + c)*512 + db*64 + d0) = v;
  }
}

// ---------- 1. x_flat = mean over 49 positions ----------
__global__ __launch_bounds__(256) void k_xflat(const void* __restrict__ x,
                                               const int* __restrict__ flag,
                                               float* __restrict__ xflat){
  int bf = flag[0];
  int i = blockIdx.x*256 + threadIdx.x;       // 0..16383
  int b = i >> 9, dch = i & 511;
  float s = 0.f;
  for (int l = 0; l < L_; l++) s += ldf(x, ((size_t)(b*L_ + l))*D_ + dch, bf);
  xflat[i] = s * (1.f/49.f);
}

// ---------- 2. gating (single block) ----------
__global__ __launch_bounds__(128) void k_gate(const void* __restrict__ wg,
                                              const void* __restrict__ bg,
                                              const int* __restrict__ flag,
                                              const float* __restrict__ xflat,
                                              int* __restrict__ topi, float* __restrict__ topv,
                                              void* __restrict__ out){
  __shared__ float logits[B_*E_];
  __shared__ float raw[B_*E_];
  __shared__ int   sel[B_];
  __shared__ float den[E_], auxp[E_];
  int bf = flag[0];
  int t = threadIdx.x;
  {
    int b = t >> 2, e = t & 3;
    float acc = ldf(bg, e, bf);
    const float* xr = xflat + b*D_;
    for (int d = 0; d < D_; d++) acc = fmaf(xr[d], ldf(wg, d*E_ + e, bf), acc);
    logits[t] = acc;
  }
  __syncthreads();
  if (t < B_){
    float l0=logits[t*4+0], l1=logits[t*4+1], l2=logits[t*4+2], l3=logits[t*4+3];
    float m = fmaxf(fmaxf(l0,l1), fmaxf(l2,l3));
    float e0=expf(l0-m), e1=expf(l1-m), e2=expf(l2-m), e3=expf(l3-m);
    float s = e0+e1+e2+e3;
    float r[4] = {e0/s, e1/s, e2/s, e3/s};
    int i1 = 0; float v1 = r[0];
    for (int e = 1; e < 4; e++) if (r[e] > v1){ v1 = r[e]; i1 = e; }
    int i2 = -1; float v2 = -1.f;
    for (int e = 0; e < 4; e++){ if (e == i1) continue; if (r[e] > v2){ v2 = r[e]; i2 = e; } }
    if (i1 < 0 || i1 > 3) i1 = 0;
    if (i2 < 0 || i2 > 3) i2 = (i1 + 1) & 3;
    sel[t] = (1<<i1) | (1<<i2);
    for (int e = 0; e < 4; e++) raw[t*4+e] = r[e];
  }
  __syncthreads();
  if (t < E_){
    float dn = 0.f, imp = 0.f, ld = 0.f;
    for (int b = 0; b < B_; b++){
      float r = raw[b*4+t];
      int bit = (sel[b] >> t) & 1;
      if (bit) dn += r;
      imp += r; ld += (float)bit;
    }
    den[t] = dn + 1e-6f;
    imp *= (1.f/B_); ld *= (1.f/B_);
    float df = ld - imp; auxp[t] = df*df;
  }
  __syncthreads();
  if (t == 0){
    float a = 0.01f * 0.25f * (auxp[0]+auxp[1]+auxp[2]+auxp[3]);
    if (bf) ((unsigned short*)out)[16384] = f2bfu(a);
    else    ((float*)out)[16384] = a;
  }
  if (t < B_){
    float gs[4];
    for (int e = 0; e < 4; e++){
      int bit = (sel[t] >> e) & 1;
      gs[e] = bit ? raw[t*4+e] * 40.f / den[e] : 0.f;   // capacity = int(1.25*32) = 40
    }
    int i1 = 0; float v1 = gs[0];
    for (int e = 1; e < 4; e++) if (gs[e] > v1){ v1 = gs[e]; i1 = e; }
    int i2 = -1; float v2 = -1e30f;
    for (int e = 0; e < 4; e++){ if (e == i1) continue; if (gs[e] > v2){ v2 = gs[e]; i2 = e; } }
    if (i1 < 0 || i1 > 3) i1 = 0;
    if (i2 < 0 || i2 > 3) i2 = (i1 + 1) & 3;
    topi[t*2+0] = i1; topv[t*2+0] = v1;
    topi[t*2+1] = i2; topv[t*2+1] = v2;
  }
}

// ---------- 3. in_proj via MFMA: xz[49x1024] = X[49x512] @ W[e][512x1024] ----------
// grid (64 jobs, 8 n-tiles of 128). Wave w handles M-tile rows w*16..w*16+15
// (rows>=49 clamped, unstored), 8 N-subtiles of 16. A,B read direct from global
// (X rows d-contiguous; WT[e][c][d] pre-transposed so B cols are d-contiguous).
__global__ __launch_bounds__(256) void k_inproj_mfma(const void* __restrict__ x,
                                                     const unsigned short* __restrict__ wt,
                                                     const void* __restrict__ bias,
                                                     const int* __restrict__ flag,
                                                     const int* __restrict__ topi,
                                                     float* __restrict__ xin,
                                                     unsigned short* __restrict__ zbuf){
  int job = blockIdx.x, nt = blockIdx.y;
  int bf = flag[0];
  int b = job >> 1;
  int e = topi[job];
  int t = threadIdx.x;
  int wave = t >> 6, lane = t & 63;
  int l16 = lane & 15, quad = lane >> 4;
  int arow = wave*16 + l16; if (arow > 48) arow = 48;   // pad rows duplicate row 48
  size_t abase = ((size_t)(b*L_ + arow))*D_;
  int ct = nt*128;
  size_t bbase = ((size_t)(e*1024 + ct + l16))*D_;      // + s*16*512 + k
  f32x4v acc[8] = {};
  for (int k0 = 0; k0 < 512; k0 += 32){
    int k = k0 + quad*8;
    U4 a;
    if (bf){
      a.u = *(const uint4*)((const unsigned short*)x + abase + k);
    } else {
      const float* xp = (const float*)x + abase + k;
      float4 f0 = *(const float4*)xp, f1 = *(const float4*)(xp+4);
      a.u.x = (unsigned)f2bfu(f0.x) | ((unsigned)f2bfu(f0.y) << 16);
      a.u.y = (unsigned)f2bfu(f0.z) | ((unsigned)f2bfu(f0.w) << 16);
      a.u.z = (unsigned)f2bfu(f1.x) | ((unsigned)f2bfu(f1.y) << 16);
      a.u.w = (unsigned)f2bfu(f1.z) | ((unsigned)f2bfu(f1.w) << 16);
    }
    #pragma unroll
    for (int s = 0; s < 8; s++){
      U4 bb;
      bb.u = *(const uint4*)(wt + bbase + (size_t)s*16*D_ + k);
      acc[s] = __builtin_amdgcn_mfma_f32_16x16x32_bf16(a.s, bb.s, acc[s], 0, 0, 0);
    }
  }
  int rb = wave*16 + quad*4;
  #pragma unroll
  for (int s = 0; s < 8; s++){
    int c = ct + s*16 + l16;
    float bv = ldf(bias, (size_t)e*1024 + c, bf);
    #pragma unroll
    for (int r = 0; r < 4; r++){
      int row = rb + r;
      if (row < L_){
        float v = acc[s][r] + bv;
        if (ct < 512) xin [(size_t)job*25088 + row*D_ + c] = v;
        else          zbuf[(size_t)job*25088 + row*D_ + (c - 512)] = f2bfu(v);
      }
    }
  }
}

// ---------- 4. depthwise conv 3x3 + bias + silu -> xc[job][p][d] (fp32) ----------
__global__ __launch_bounds__(256) void k_conv(const void* __restrict__ cw,
                                              const void* __restrict__ cb,
                                              const int* __restrict__ flag,
                                              const int* __restrict__ topi,
                                              const float* __restrict__ xin,
                                              float* __restrict__ xc){
  int bf = flag[0];
  int job = blockIdx.x, p = blockIdx.y, t = threadIdx.x;
  int e = topi[job];
  int h = p / 7, w = p % 7;
  const float* xb = xin + (size_t)job*25088;
  #pragma unroll
  for (int rep = 0; rep < 2; rep++){
    int dch = t + rep*256;
    float acc = ldf(cb, e*D_ + dch, bf);
    size_t wp = ((size_t)(e*D_ + dch))*9;
    #pragma unroll
    for (int dy = 0; dy < 3; dy++){
      int hh = h + dy - 1; if (hh < 0 || hh >= 7) continue;
      #pragma unroll
      for (int dx = 0; dx < 3; dx++){
        int ww = w + dx - 1; if (ww < 0 || ww >= 7) continue;
        acc = fmaf(xb[(size_t)(hh*7+ww)*D_ + dch], ldf(cw, wp + dy*3+dx, bf), acc);
      }
    }
    xc[(size_t)job*25088 + (size_t)p*D_ + dch] = acc * (1.f/(1.f+expf(-acc)));
  }
}

// ---------- 5. x_proj: LDS-staged weights, coalesced ----------
__global__ __launch_bounds__(256) void k_xproj(const void* __restrict__ xpw,
                                               const int* __restrict__ flag,
                                               const int* __restrict__ topi,
                                               const float* __restrict__ xc,
                                               float* __restrict__ xdbl){
  int bf = flag[0];
  int job = blockIdx.x, k = blockIdx.y, z = blockIdx.z;
  int t = threadIdx.x;
  int c = t & 63, lq = t >> 6;                 // lq = wave id (l is wave-uniform)
  int e = topi[job];
  __shared__ unsigned short wl[64*512];        // 64 KB, packed [s][c][8], s = d/8
  size_t wgbase = ((size_t)(e*KD_+k))*64*512;
  #pragma unroll
  for (int it = 0; it < 16; it++){
    int idx = it*256 + t;                      // ushort8-chunk id, 4096 total
    int cc = idx >> 6, s = idx & 63;
    unsigned short* dst = &wl[s*512 + cc*8];
    if (bf){
      *(uint4*)dst = *(const uint4*)((const unsigned short*)xpw + wgbase + (size_t)cc*512 + s*8);
    } else {
      const float4* g = (const float4*)((const float*)xpw + wgbase + (size_t)cc*512 + s*8);
      float4 a = g[0], b = g[1];
      dst[0]=f2bfu(a.x); dst[1]=f2bfu(a.y); dst[2]=f2bfu(a.z); dst[3]=f2bfu(a.w);
      dst[4]=f2bfu(b.x); dst[5]=f2bfu(b.y); dst[6]=f2bfu(b.z); dst[7]=f2bfu(b.w);
    }
  }
  __syncthreads();
  const float* xcb = xc + (size_t)job*25088;
  float* outb = xdbl + ((size_t)(job*KD_+k))*3136;
  #pragma unroll
  for (int ti = 0; ti < 7; ti++){
    int l2 = ti*4 + lq;                        // 0..27
    int l = 2*l2 + z;                          // even/odd split over blockIdx.z
    if (l >= L_) continue;
    int m = dirmap(k, l);
    const float4* xr = (const float4*)(xcb + (size_t)m*D_);
    float a0=0.f, a1=0.f, a2=0.f, a3=0.f;
    for (int s = 0; s < 64; s++){
      uint4 w = *(const uint4*)&wl[s*512 + c*8];
      float4 x0 = xr[2*s], x1 = xr[2*s+1];
      float2 p0 = bfp(w.x), p1 = bfp(w.y), p2 = bfp(w.z), p3 = bfp(w.w);
      a0 = fmaf(x0.x, p0.x, a0); a1 = fmaf(x0.y, p0.y, a1);
      a2 = fmaf(x0.z, p1.x, a2); a3 = fmaf(x0.w, p1.y, a3);
      a0 = fmaf(x1.x, p2.x, a0); a1 = fmaf(x1.y, p2.y, a1);
      a2 = fmaf(x1.z, p3.x, a2); a3 = fmaf(x1.w, p3.y, a3);
    }
    outb[l*64 + c] = (a0+a1)+(a2+a3);
  }
}

// ---------- 6. fused dt_proj + softplus + selective scan + combine ----------
__global__ __launch_bounds__(256) void k_scan(const void* __restrict__ dtw,
                                              const void* __restrict__ dtb_,
                                              const void* __restrict__ alog,
                                              const void* __restrict__ ds_,
                                              const int* __restrict__ flag,
                                              const int* __restrict__ topi,
                                              const float* __restrict__ xc,
                                              const float* __restrict__ xdbl,
                                              float* __restrict__ ycomb){
  int bf = flag[0];
  int job = blockIdx.x, k = blockIdx.y, half = blockIdx.z;
  int t = threadIdx.x;
  int d = half*256 + t;
  int e = topi[job];
  __shared__ float xdl[3136];                 // [l][64] : dt(32) | B(16) | C(16)
  const float* src = xdbl + ((size_t)(job*KD_+k))*3136;
  for (int i = t; i < 3136; i += 256) xdl[i] = src[i];
  int ek = e*KD_ + k;
  float w32[RK_];
  #pragma unroll
  for (int q = 0; q < 4; q++){
    f8s wr = ldf8(dtw, ((size_t)ek*D_ + d)*RK_ + q*8, bf);
    #pragma unroll
    for (int j = 0; j < 8; j++) w32[q*8+j] = wr.v[j];
  }
  float A[NS_];
  #pragma unroll
  for (int q = 0; q < 2; q++){
    f8s ar = ldf8(alog, ((size_t)ek*D_ + d)*NS_ + q*8, bf);
    #pragma unroll
    for (int j = 0; j < 8; j++) A[q*8+j] = -expf(ar.v[j]);
  }
  float dtb = ldf(dtb_, (size_t)ek*D_ + d, bf);
  float Dsv = ldf(ds_, (size_t)ek*D_ + d, bf);
  __syncthreads();
  float h[NS_];
  #pragma unroll
  for (int n = 0; n < NS_; n++) h[n] = 0.f;
  const float* xcb = xc + (size_t)job*25088;
  float* ycb = ycomb + (size_t)job*25088;
  for (int l = 0; l < L_; l++){
    const float* xr = &xdl[l*64];
    float dtr = dtb;
    #pragma unroll
    for (int r = 0; r < RK_; r++) dtr = fmaf(xr[r], w32[r], dtr);
    float dt = dtr > 20.f ? dtr : log1pf(expf(dtr));   // softplus
    int m = dirmap(k, l);
    float x_t = xcb[(size_t)m*D_ + d];
    float dtx = dt * x_t;
    float y = 0.f;
    #pragma unroll
    for (int n = 0; n < NS_; n++){
      h[n] = fmaf(h[n], expf(dt*A[n]), dtx * xr[32+n]);
      y = fmaf(h[n], xr[48+n], y);
    }
    atomicAdd(&ycb[(size_t)m*D_ + d], fmaf(Dsv, x_t, y));
  }
}

// ---------- 7. per-job: LN over d at each p, *silu(z), pool, LN, *topv ----------
__device__ __forceinline__ void bred(float& s, float& ss, float* red){
  __syncthreads();
  #pragma unroll
  for (int o = 32; o > 0; o >>= 1){
    s  += __shfl_down(s,  o, 64);
    ss += __shfl_down(ss, o, 64);
  }
  int wid = threadIdx.x >> 6, lane = threadIdx.x & 63;
  if (lane == 0){ red[wid] = s; red[4+wid] = ss; }
  __syncthreads();
  s  = red[0]+red[1]+red[2]+red[3];
  ss = red[4]+red[5]+red[6]+red[7];
}

__global__ __launch_bounds__(256) void k_final(const void* __restrict__ og,
                                               const void* __restrict__ ob,
                                               const void* __restrict__ ng,
                                               const void* __restrict__ nb,
                                               const int* __restrict__ flag,
                                               const int* __restrict__ topi,
                                               const float* __restrict__ topv,
                                               const float* __restrict__ ycomb,
                                               const unsigned short* __restrict__ zbuf,
                                               float* __restrict__ slot){
  __shared__ float red[8];
  int bf = flag[0];
  int job = blockIdx.x, t = threadIdx.x;
  int e = topi[job]; float gv = topv[job];
  int d0 = t, d1 = t + 256;
  const float* yc = ycomb + (size_t)job*25088;
  const unsigned short* zb = zbuf + (size_t)job*25088;
  float g0 = ldf(og, e*D_+d0, bf), g1 = ldf(og, e*D_+d1, bf);
  float o0 = ldf(ob, e*D_+d0, bf), o1 = ldf(ob, e*D_+d1, bf);
  float p0 = 0.f, p1 = 0.f;
  for (int p = 0; p < L_; p++){
    float v0 = yc[p*D_+d0], v1 = yc[p*D_+d1];
    float s = v0+v1, ss = v0*v0 + v1*v1;
    bred(s, ss, red);
    float mu = s*(1.f/512.f);
    float var = ss*(1.f/512.f) - mu*mu;
    float rs = rsqrtf(var + 1e-5f);
    float z0 = bf2f(zb[p*D_ + d0]), z1 = bf2f(zb[p*D_ + d1]);
    p0 += ((v0-mu)*rs*g0 + o0) * silu_f(z0);
    p1 += ((v1-mu)*rs*g1 + o1) * silu_f(z1);
  }
  p0 *= (1.f/49.f); p1 *= (1.f/49.f);
  float s = p0+p1, ss = p0*p0 + p1*p1;
  bred(s, ss, red);
  float mu = s*(1.f/512.f);
  float var = ss*(1.f/512.f) - mu*mu;
  float rs = rsqrtf(var + 1e-5f);
  slot[(size_t)job*D_ + d0] = ((p0-mu)*rs*ldf(ng, e*D_+d0, bf) + ldf(nb, e*D_+d0, bf)) * gv;
  slot[(size_t)job*D_ + d1] = ((p1-mu)*rs*ldf(ng, e*D_+d1, bf) + ldf(nb, e*D_+d1, bf)) * gv;
}

// ---------- 8. mix the two slots per batch -> out ----------
__global__ __launch_bounds__(256) void k_mix(const float* __restrict__ slot,
                                             const int* __restrict__ flag,
                                             void* __restrict__ out){
  int bf = flag[0];
  int i = blockIdx.x*256 + threadIdx.x;       // 0..16383
  int b = i >> 9, d = i & 511;
  float v = slot[(size_t)(2*b)*D_ + d] + slot[(size_t)(2*b+1)*D_ + d];
  if (bf) ((unsigned short*)out)[i] = f2bfu(v);
  else    ((float*)out)[i] = v;
}

extern "C" void kernel_launch(void* const* d_in, const int* in_sizes, int n_in,
                              void* d_out, int out_size, void* d_ws, size_t ws_size,
                              hipStream_t stream){
  const void* x    = d_in[0];
  const void* wg   = d_in[1];
  const void* bg   = d_in[2];
  const void* ipw  = d_in[3];
  const void* ipb  = d_in[4];
  const void* cw   = d_in[5];
  const void* cb   = d_in[6];
  const void* xpw  = d_in[7];
  const void* dtw  = d_in[8];
  const void* dtb  = d_in[9];
  const void* alog = d_in[10];
  const void* dss  = d_in[11];
  const void* ogg  = d_in[12];
  const void* obb  = d_in[13];
  const void* ngg  = d_in[14];
  const void* nbb  = d_in[15];
  float* wsf = (float*)d_ws;
  int*   flag  = (int*)d_ws;                         // [0]
  int*   topi  = (int*)d_ws + 16;                    // 16..80
  float* topv  = wsf + 96;                           // 96..160
  float* xflat = wsf + 256;                          // 16384
  float* xc    = wsf + 16640;                        // 64*49*512 = 1605632
  float* xdbl  = wsf + 1622272;                      // 64*4*49*64 = 802816
  float* r1    = wsf + 2425088;                      // xin, later ycomb: 1605632
  unsigned short* zbuf = (unsigned short*)(wsf + 4030720); // 1605632 bf16
  float* slot  = wsf + 4833536;                      // 64*512 = 32768 (end ~18.6MB)
  // WT (4 MB, bf16 [e][c][d]) lives in the xc region: only used before k_conv writes xc.
  unsigned short* wtrans = (unsigned short*)xc;

  k_detect<<<1, 256, 0, stream>>>((const unsigned short*)x, flag);
  k_wtrans<<<dim3(4,16,8), 256, 0, stream>>>(ipw, flag, wtrans);
  k_xflat <<<64, 256, 0, stream>>>(x, flag, xflat);
  k_gate  <<<1, 128, 0, stream>>>(wg, bg, flag, xflat, topi, topv, d_out);
  k_inproj_mfma<<<dim3(64,8), 256, 0, stream>>>(x, wtrans, ipb, flag, topi, r1, zbuf);
  k_conv  <<<dim3(64,49), 256, 0, stream>>>(cw, cb, flag, topi, r1, xc);
  hipMemsetAsync(r1, 0, (size_t)1605632*4, stream);  // r1 becomes ycomb
  k_xproj <<<dim3(64,4,2),256, 0, stream>>>(xpw, flag, topi, xc, xdbl);
  k_scan  <<<dim3(64,4,2),256, 0, stream>>>(dtw, dtb, alog, dss, flag, topi, xc, xdbl, r1);
  k_final <<<64, 256, 0, stream>>>(ogg, obb, ngg, nbb, flag, topi, topv, r1, zbuf, slot);
  k_mix   <<<64, 256, 0, stream>>>(slot, flag, d_out);
}